// Round 1
// 169.934 us; speedup vs baseline: 1.5240x; 1.5240x over previous
//
#include <hip/hip_runtime.h>

// CausalGraphReasoning fused v3: B=256, N=196, D=768, H=256, K=8
// One workgroup per batch (256 blocks). v3: 1024 thr / 16 waves (was 512/8) --
// LDS still limits to 1 block/CU, so waves/CU 8->16 (occupancy 25%->50%).
// Per-wave work halved everywhere; top-8 now 1 row/wave with packed-key
// (value|~idx) argmax: 1 shuffle + 1 v_max_u32 per butterfly step.
// stage1: nodes=X@Wn+bn (3-deep X pipeline, dbuf LDS, 1 barrier/step)
// strips: sim(16 rows) -> top8+gather -> msg GEMM -> updated -> global
// restage: updated -> nodesS via global_load_lds (pre-swizzled source)
// stage5: out = updated@Wo+bo

#define NN 196
#define MM 208
#define DD 768
#define HH 256

typedef unsigned short u16;
typedef __attribute__((ext_vector_type(8))) short short8;
typedef __attribute__((ext_vector_type(4))) float f32x4;

#define GLD16(gp, lp) __builtin_amdgcn_global_load_lds( \
    (__attribute__((address_space(1))) const void*)(gp), \
    (__attribute__((address_space(3))) void*)(lp), 16, 0, 0)

__device__ __forceinline__ u16 f2b(float f) {
  union { float f; unsigned int i; } c; c.f = f;
  unsigned int x = c.i;
  return (u16)((x + 0x7fffu + ((x >> 16) & 1u)) >> 16);
}
__device__ __forceinline__ float b2f(u16 u) {
  union { float f; unsigned int i; } c; c.i = ((unsigned int)u) << 16; return c.f;
}

// ------------- weight transpose + f32->bf16 (verified) -------------
__global__ __launch_bounds__(256) void transpose_w(
    const float* __restrict__ in, u16* __restrict__ out, int R, int C)
{
  __shared__ u16 tile[32][33];
  int bx = blockIdx.x, by = blockIdx.y;
  int t = threadIdx.x;
  int i = t >> 5, j = t & 31;
  #pragma unroll
  for (int s = 0; s < 32; s += 8)
    tile[i + s][j] = f2b(in[(size_t)(by * 32 + i + s) * C + bx * 32 + j]);
  __syncthreads();
  #pragma unroll
  for (int s = 0; s < 32; s += 8)
    out[(size_t)(bx * 32 + i + s) * R + by * 32 + j] = tile[j][i + s];
}

// LDS (bytes): nodesS [208][32 slots16B] swz ^(r&7)              @0      106496
//   stage1:  Xbuf0/Xbuf1 [208][4 slots] swz ^((r>>1)&3)          @106496 2x13312
//   strips:  simS0/simS1 f32 [16][208]                           @106496 2x13312
//            neighS0/neighS1 [16][32 slots] swz ^(lr&7)          @133120 2x8192
__global__ __launch_bounds__(1024, 4) void fused_batch(
    const float* __restrict__ X, const u16* __restrict__ WnT,
    const float* __restrict__ bn, const u16* __restrict__ WmT,
    const float* __restrict__ bm, const u16* __restrict__ WoT,
    const float* __restrict__ bo, u16* __restrict__ updatedG,
    float* __restrict__ outG, float* __restrict__ valsG)
{
  extern __shared__ __align__(16) u16 smem[];
  u16* nodesS = smem;
  u16* Xbuf0 = smem + 53248;
  u16* Xbuf1 = smem + 53248 + 6656;
  float* simS0 = (float*)(smem + 53248);
  float* simS1 = (float*)(smem + 53248 + 6656);
  u16* neighS0 = smem + 53248 + 13312;
  u16* neighS1 = smem + 53248 + 13312 + 4096;

  const int t = threadIdx.x;
  const int w = t >> 6;          // 0..15
  const int lane = t & 63;
  const int l15 = lane & 15;
  const int kg = lane >> 4;
  const int b = blockIdx.x;
  const float* Xb = X + (size_t)b * (NN * DD);
  u16* updGb = updatedG + (size_t)b * MM * HH;

  // ================= stage 1: nodes = X @ Wn + bn =================
  f32x4 acc[13];
  #pragma unroll
  for (int fr = 0; fr < 13; ++fr) acc[fr] = (f32x4)0.0f;

  const bool xact = (t < 832);          // 4 threads per row, 208 rows
  const int xrow = t >> 2;
  const int xr2 = (xrow < NN) ? xrow : (NN - 1);
  const int xcb = (t & 3) * 8;
  const int xsw = (xrow >> 1) & 3;
  const int xj0 = t & 3;

  f32x4 xsA[2], xsB[2], xsC[2];
  short8 bfrC0, bfrN0;

#define S1_ISSUE(SET, KT) do { \
    const float* xp_ = Xb + (size_t)xr2 * DD + (KT) * 32 + xcb; \
    SET[0] = *(const f32x4*)(xp_); SET[1] = *(const f32x4*)(xp_ + 4); \
  } while (0)

#define S1_COMMIT(SET, BUFW) do { \
    short8 v_; \
    _Pragma("unroll") for (int q_ = 0; q_ < 8; ++q_) v_[q_] = (short)f2b(SET[q_ >> 2][q_ & 3]); \
    *(short8*)((BUFW) + xrow * 32 + ((xj0 ^ xsw) << 3)) = v_; \
  } while (0)

#define S1_STEP(KT, XI, XC, BUFR, BUFW) do { \
    if (xact && (KT) + 3 < 24) S1_ISSUE(XI, (KT) + 3); \
    if ((KT) + 1 < 24) \
      bfrN0 = *(const short8*)(WnT + (size_t)(w * 16 + l15) * DD + ((KT) + 1) * 32 + kg * 8); \
    __builtin_amdgcn_s_setprio(1); \
    _Pragma("unroll") for (int fr_ = 0; fr_ < 13; ++fr_) { \
      const int r_ = fr_ * 16 + l15; \
      short8 a_ = *(const short8*)((BUFR) + r_ * 32 + ((kg ^ ((r_ >> 1) & 3)) << 3)); \
      acc[fr_] = __builtin_amdgcn_mfma_f32_16x16x32_bf16(a_, bfrC0, acc[fr_], 0, 0, 0); \
    } \
    __builtin_amdgcn_s_setprio(0); \
    if (xact && (KT) + 1 < 24) S1_COMMIT(XC, BUFW); \
    __syncthreads(); \
    bfrC0 = bfrN0; \
  } while (0)

  if (xact) { S1_ISSUE(xsA, 0); S1_ISSUE(xsB, 1); S1_ISSUE(xsC, 2); S1_COMMIT(xsA, Xbuf0); }
  bfrC0 = *(const short8*)(WnT + (size_t)(w * 16 + l15) * DD + kg * 8);
  __syncthreads();

  for (int kb = 0; kb < 24; kb += 6) {
    S1_STEP(kb + 0, xsA, xsB, Xbuf0, Xbuf1);
    S1_STEP(kb + 1, xsB, xsC, Xbuf1, Xbuf0);
    S1_STEP(kb + 2, xsC, xsA, Xbuf0, Xbuf1);
    S1_STEP(kb + 3, xsA, xsB, Xbuf1, Xbuf0);
    S1_STEP(kb + 4, xsB, xsC, Xbuf0, Xbuf1);
    S1_STEP(kb + 5, xsC, xsA, Xbuf1, Xbuf0);
  }

  // epilogue: nodes -> nodesS (+bias), swizzled
  {
    const float bnv = bn[w * 16 + l15];
    #pragma unroll
    for (int fr = 0; fr < 13; ++fr)
      #pragma unroll
      for (int ri = 0; ri < 4; ++ri) {
        const int r = fr * 16 + kg * 4 + ri;
        const int c = w * 16 + l15;
        nodesS[r * 256 + (((c >> 3) ^ (r & 7)) << 3) + (c & 7)] = f2b(acc[fr][ri] + bnv);
      }
  }
  __syncthreads();

  // ============ strips: sim -> top8+gather -> msg -> updated ============
  const float bmv = bm[w * 16 + l15];

  for (int s = 0; s < 13; ++s) {
    float* simSp = (s & 1) ? simS1 : simS0;
    u16* neighSp = (s & 1) ? neighS1 : neighS0;

    // ---- phase A: sim strip MFMA (wave w -> column tile w, 13 tiles) ----
    if (w < 13) {
      f32x4 s0 = (f32x4)0.0f;
      __builtin_amdgcn_s_setprio(1);
      #pragma unroll
      for (int kt = 0; kt < 8; ++kt) {
        const int ar = s * 16 + l15;
        const int ja = kt * 4 + kg;
        short8 av = *(const short8*)(nodesS + ar * 256 + ((ja ^ (ar & 7)) << 3));
        const int br = w * 16 + l15;
        short8 bv = *(const short8*)(nodesS + br * 256 + ((ja ^ (br & 7)) << 3));
        s0 = __builtin_amdgcn_mfma_f32_16x16x32_bf16(av, bv, s0, 0, 0, 0);
      }
      __builtin_amdgcn_s_setprio(0);
      #pragma unroll
      for (int ri = 0; ri < 4; ++ri) simSp[(kg * 4 + ri) * MM + w * 16 + l15] = s0[ri];
    }
    __syncthreads();

    // ---- phase B: top-8 + gather (wave w -> row w) ----
    {
      const int lr = w;
      const int n = s * 16 + lr;
      if (n < NN) {
        const float* srow = simSp + lr * MM;
        // packed sortable key: top 24 bits = monotonic(f32), low 8 = 255-col
        // (tie -> lower col wins, matching jax top_k)
        unsigned int v[4];
        #pragma unroll
        for (int i = 0; i < 4; ++i) {
          const int c = i * 64 + lane;
          const float f = (c < NN && c != n) ? srow[c] : -1e30f;
          union { float f; unsigned int i; } cv; cv.f = f;
          const unsigned int u = cv.i;
          const unsigned int key = u ^ ((u & 0x80000000u) ? 0xFFFFFFFFu : 0x80000000u);
          v[i] = (key & 0xFFFFFF00u) | (255u - (unsigned int)c);
        }
        int kcol[8];
        #pragma unroll
        for (int it = 0; it < 8; ++it) {
          unsigned int p0 = v[0] > v[1] ? v[0] : v[1];
          unsigned int p1 = v[2] > v[3] ? v[2] : v[3];
          unsigned int pk = p0 > p1 ? p0 : p1;
          #pragma unroll
          for (int off = 32; off >= 1; off >>= 1) {
            const unsigned int o = (unsigned int)__shfl_xor((int)pk, off);
            pk = o > pk ? o : pk;
          }
          const int cm = 255 - (int)(pk & 255u);
          kcol[it] = cm;
          if (lane == 0) {
            const unsigned int key = pk & 0xFFFFFF00u;
            union { float f; unsigned int i; } rv;
            rv.i = (key & 0x80000000u) ? (key ^ 0x80000000u) : ~key;
            valsG[((size_t)b * NN + n) * 8 + it] = rv.f;
          }
          if (lane == (cm & 63)) v[cm >> 6] = 0u;
        }
        float a0 = 0.f, a1 = 0.f, a2 = 0.f, a3 = 0.f;
        #pragma unroll
        for (int j = 0; j < 8; ++j) {
          const int kr = kcol[j];
          const uint2 u = *(const uint2*)(nodesS + kr * 256 + (((lane >> 1) ^ (kr & 7)) << 3) + (lane & 1) * 4);
          a0 += b2f((u16)(u.x & 0xffff)); a1 += b2f((u16)(u.x >> 16));
          a2 += b2f((u16)(u.y & 0xffff)); a3 += b2f((u16)(u.y >> 16));
        }
        const int jN = lane >> 1;
        u16* np = neighSp + lr * 256 + ((jN ^ (lr & 7)) << 3) + (lane & 1) * 4;
        np[0] = f2b(a0 * 0.125f); np[1] = f2b(a1 * 0.125f);
        np[2] = f2b(a2 * 0.125f); np[3] = f2b(a3 * 0.125f);
      }
    }
    __syncthreads();

    // ---- phase C: msg GEMM (16 rows x 256, K=256) + updated -> global ----
    {
      f32x4 m0 = (f32x4)0.0f;
      __builtin_amdgcn_s_setprio(1);
      #pragma unroll
      for (int kt = 0; kt < 8; ++kt) {
        const int ja = kt * 4 + kg;
        short8 a = *(const short8*)(neighSp + l15 * 256 + ((ja ^ (l15 & 7)) << 3));
        short8 b0 = *(const short8*)(WmT + (size_t)(w * 16 + l15) * HH + kt * 32 + kg * 8);
        m0 = __builtin_amdgcn_mfma_f32_16x16x32_bf16(a, b0, m0, 0, 0, 0);
      }
      __builtin_amdgcn_s_setprio(0);
      #pragma unroll
      for (int ri = 0; ri < 4; ++ri) {
        const int r = s * 16 + kg * 4 + ri;
        const int c = w * 16 + l15;
        const float mv = m0[ri] + bmv;
        const float nodev = b2f(nodesS[r * 256 + (((c >> 3) ^ (r & 7)) << 3) + (c & 7)]);
        updGb[(size_t)r * HH + c] = f2b(nodev + fmaxf(mv, 0.0f));
      }
    }
  }

  // ============ restage: updated -> nodesS (pre-swizzled source) ============
  __syncthreads();
  #pragma unroll
  for (int q = 0; q < 7; ++q) {
    const int si = q * 1024 + t;
    if (si < 6656) {
      const int r = si >> 5;
      const int jj = si & 31;
      const int j = jj ^ (r & 7);
      GLD16(updGb + (size_t)r * HH + j * 8, nodesS + si * 8);
    }
  }
  __syncthreads();

  // ================= stage 5: out = updated @ Wo + bo =================
  for (int ch = 0; ch < 3; ++ch) {
    f32x4 oacc[13];
    #pragma unroll
    for (int fr = 0; fr < 13; ++fr) oacc[fr] = (f32x4)0.0f;
    __builtin_amdgcn_s_setprio(1);
    #pragma unroll
    for (int kt = 0; kt < 8; ++kt) {
      short8 bfr = *(const short8*)(WoT + (size_t)(ch * 256 + w * 16 + l15) * HH + kt * 32 + kg * 8);
      #pragma unroll
      for (int fr = 0; fr < 13; ++fr) {
        const int r = fr * 16 + l15;
        const int ja = kt * 4 + kg;
        short8 a = *(const short8*)(nodesS + r * 256 + ((ja ^ (r & 7)) << 3));
        oacc[fr] = __builtin_amdgcn_mfma_f32_16x16x32_bf16(a, bfr, oacc[fr], 0, 0, 0);
      }
    }
    __builtin_amdgcn_s_setprio(0);
    const float bov = bo[ch * 256 + w * 16 + l15];
    #pragma unroll
    for (int fr = 0; fr < 13; ++fr)
      #pragma unroll
      for (int ri = 0; ri < 4; ++ri) {
        const int r = fr * 16 + kg * 4 + ri;
        if (r < NN)
          outG[((size_t)b * NN + r) * DD + ch * 256 + w * 16 + l15] =
              oacc[fr][ri] + bov;
      }
  }
}

extern "C" void kernel_launch(void* const* d_in, const int* in_sizes, int n_in,
                              void* d_out, int out_size, void* d_ws, size_t ws_size,
                              hipStream_t stream) {
  const float* X  = (const float*)d_in[0];
  const float* Wn = (const float*)d_in[1];
  const float* bn = (const float*)d_in[2];
  const float* Wm = (const float*)d_in[3];
  const float* bm = (const float*)d_in[4];
  const float* Wo = (const float*)d_in[5];
  const float* bo = (const float*)d_in[6];

  char* p = (char*)d_ws;
  u16* WnT = (u16*)p;  p += (size_t)256 * 768 * 2;
  u16* WmT = (u16*)p;  p += (size_t)256 * 256 * 2;
  u16* WoT = (u16*)p;  p += (size_t)768 * 256 * 2;
  u16* updatedG = (u16*)p;  p += (size_t)256 * MM * HH * 2;   // 27.3 MB

  float* out  = (float*)d_out;
  float* vals = out + (size_t)256 * NN * DD;

  transpose_w<<<dim3(256 / 32, 768 / 32), 256, 0, stream>>>(Wn, WnT, 768, 256);
  transpose_w<<<dim3(256 / 32, 256 / 32), 256, 0, stream>>>(Wm, WmT, 256, 256);
  transpose_w<<<dim3(768 / 32, 256 / 32), 256, 0, stream>>>(Wo, WoT, 256, 768);

  const int smem_bytes = 149504;
  (void)hipFuncSetAttribute((const void*)fused_batch,
                            hipFuncAttributeMaxDynamicSharedMemorySize, smem_bytes);
  fused_batch<<<256, 1024, smem_bytes, stream>>>(X, WnT, bn, WmT, bm, WoT, bo,
                                                 updatedG, out, vals);
}